// Round 3
// baseline (1181.011 us; speedup 1.0000x reference)
//
#include <hip/hip_runtime.h>
#include <hip/hip_bf16.h>

#define B_ 8
#define H_ 128
#define W_ 128
#define C_ 128

using f32x4 = __attribute__((ext_vector_type(4))) float;
using s16x8 = __attribute__((ext_vector_type(8))) short;
using us4   = __attribute__((ext_vector_type(4))) unsigned short;

// mish(x) = x * tanh(softplus(x)) = x * (t^2 + 2t) / (t^2 + 2t + 2), t = e^x
__device__ __forceinline__ float mish_f(float x) {
    float t = __expf(fminf(x, 20.0f));
    float u = t * (t + 2.0f);
    return x * u / (u + 2.0f);
}

__device__ __forceinline__ int swz_row(int blk) {
    return ((blk & 7) << 7) | (blk >> 3);
}

// fp32 -> bf16 round-to-nearest-even on raw bits
__device__ __forceinline__ unsigned short f2bf_rne(float x) {
    unsigned u = __builtin_bit_cast(unsigned, x);
    u += 0x7FFFu + ((u >> 16) & 1u);
    return (unsigned short)(u >> 16);
}
__device__ __forceinline__ float bf2f(unsigned short h) {
    unsigned u = ((unsigned)h) << 16;
    return __builtin_bit_cast(float, u);
}
// hw conversion path (RNE, same bits as f2bf_rne for finite inputs)
__device__ __forceinline__ unsigned short f2bf_hw(float x) {
    return __bfloat16_as_ushort(__float2bfloat16(x));
}

// unaligned (4B-aligned) float4 load
__device__ __forceinline__ f32x4 load4u(const float* p) {
    f32x4 v;
    __builtin_memcpy(&v, p, 16);
    return v;
}

// ---------------------------------------------------------------------------
// 1) bilinear backward warp
// ---------------------------------------------------------------------------
__global__ __launch_bounds__(256) void warp_kernel(
    const float* __restrict__ nxt, const float* __restrict__ flo,
    float* __restrict__ nxtw)
{
    const int tid = threadIdx.x;
    const int c   = tid & 127;
    const int pix = blockIdx.x * 2 + (tid >> 7);
    const int b   = pix >> 14;
    const int rem = pix & 16383;
    const int y   = rem >> 7;
    const int x   = rem & 127;

    const float fx = flo[(size_t)pix * 2 + 0];
    const float fy = flo[(size_t)pix * 2 + 1];
    const float xf = (float)x + fx;
    const float yf = (float)y + fy;
    const int x0 = (int)xf;
    const int y0 = (int)yf;
    const int x0c = min(max(x0, 0), W_ - 1);
    const int x1c = min(max(x0 + 1, 0), W_ - 1);
    const int y0c = min(max(y0, 0), H_ - 1);
    const int y1c = min(max(y0 + 1, 0), H_ - 1);
    const float x0f = (float)x0c, x1f = (float)x1c;
    const float y0f = (float)y0c, y1f = (float)y1c;
    const float wa = (x1f - xf) * (y1f - yf);
    const float wb = (x1f - xf) * (yf - y0f);
    const float wc = (xf - x0f) * (y1f - yf);
    const float wd = (xf - x0f) * (yf - y0f);

    const float* base = nxt + (size_t)b * H_ * W_ * C_;
    const float Ia = base[((size_t)y0c * W_ + x0c) * C_ + c];
    const float Ib = base[((size_t)y1c * W_ + x0c) * C_ + c];
    const float Ic = base[((size_t)y0c * W_ + x1c) * C_ + c];
    const float Id = base[((size_t)y1c * W_ + x1c) * C_ + c];
    nxtw[(size_t)pix * C_ + c] = wa * Ia + wb * Ib + wc * Ic + wd * Id;
}

// ---------------------------------------------------------------------------
// 2) cost volume via MFMA (verified in R2: off the critical path)
// ---------------------------------------------------------------------------
__global__ __launch_bounds__(1024, 4) void costvol_mfma_kernel(
    const float* __restrict__ prv, const float* __restrict__ nxtw,
    float* __restrict__ cost)
{
    constexpr int NSTR = 40;                 // shorts per s-position (80 B, 16B-mult)
    __shared__ unsigned short Nhi[2][144 * NSTR];   // 11520 B each buf
    __shared__ unsigned short Nlo[2][144 * NSTR];
    __shared__ float scr[8][512];                   // 16 KB epilogue scratch

    const int tid  = threadIdx.x;
    const int lane = tid & 63;
    const int wv   = tid >> 6;               // 0..15
    const int w    = wv >> 1;                // x-tile 0..7
    const int nt   = wv & 1;                 // n-half 0..1
    const int r    = swz_row(blockIdx.x);    // b*H + y
    const int y    = r & 127;
    const int b    = r >> 7;
    const int ko   = (lane >> 4) * 8;        // k offset within 32-chunk
    const int m15  = lane & 15;

    auto stageN = [&](int q, int kt, int bb) {
        if (q < 0 || q >= H_) return;        // invalid row: never read (MFMA skipped)
        const float* nb = nxtw + ((size_t)(b * H_ + q) * W_) * C_ + kt * 32;
        #pragma unroll
        for (int p = 0; p < 2; ++p) {
            const int idx = tid + 1024 * p;  // 1152 float4 tasks
            if (p == 0 || tid < 128) {
                const int sm = idx >> 3;
                const int c4 = (idx & 7) * 4;
                const int gx = sm - 8;
                float4 v = make_float4(0.f, 0.f, 0.f, 0.f);
                if (gx >= 0 && gx < W_)
                    v = *(const float4*)&nb[(size_t)gx * C_ + c4];
                us4 hv, lv;
                #pragma unroll
                for (int j = 0; j < 4; ++j) {
                    const float f = ((const float*)&v)[j];
                    const unsigned short hh = f2bf_hw(f);
                    hv[j] = hh;
                    lv[j] = f2bf_hw(f - bf2f(hh));
                }
                *(us4*)&Nhi[bb][sm * NSTR + c4] = hv;
                *(us4*)&Nlo[bb][sm * NSTR + c4] = lv;
            }
        }
    };

    f32x4 acc[9];
    #pragma unroll
    for (int d = 0; d < 9; ++d) acc[d] = (f32x4){0.f, 0.f, 0.f, 0.f};

    const float* pbase = prv + ((size_t)r * W_ + (w * 16 + m15)) * C_;
    float4 pf0 = *(const float4*)&pbase[ko];
    float4 pf1 = *(const float4*)&pbase[ko + 4];

    stageN(y - 4, 0, 0);                     // prologue: step (0,0)
    __syncthreads();

    int cur = 0;
    s16x8 ahi, alo;
    for (int kt = 0; kt < 4; ++kt) {
        #pragma unroll
        for (int d = 0; d < 9; ++d) {
            if (d == 0) {                    // convert prefetched P chunk -> A frags
                #pragma unroll
                for (int j = 0; j < 8; ++j) {
                    const float f = (j < 4) ? ((const float*)&pf0)[j]
                                            : ((const float*)&pf1)[j - 4];
                    const unsigned short hh = f2bf_hw(f);
                    ahi[j] = (short)hh;
                    alo[j] = (short)f2bf_hw(f - bf2f(hh));
                }
            }
            if (d == 5 && kt < 3) {          // prefetch next P chunk
                pf0 = *(const float4*)&pbase[(kt + 1) * 32 + ko];
                pf1 = *(const float4*)&pbase[(kt + 1) * 32 + ko + 4];
            }
            {
                const int nkt = (d == 8) ? kt + 1 : kt;
                const int nd  = (d == 8) ? 0 : d + 1;
                if (nkt < 4) stageN(y + nd - 4, nkt, cur ^ 1);
            }
            const int q = y + d - 4;
            if (q >= 0 && q < H_) {
                const int boff = (w * 16 + nt * 16 + m15) * NSTR + ko;
                const s16x8 bhi = *(const s16x8*)&Nhi[cur][boff];
                const s16x8 blo = *(const s16x8*)&Nlo[cur][boff];
                acc[d] = __builtin_amdgcn_mfma_f32_16x16x32_bf16(alo, bhi, acc[d], 0, 0, 0);
                acc[d] = __builtin_amdgcn_mfma_f32_16x16x32_bf16(ahi, blo, acc[d], 0, 0, 0);
                acc[d] = __builtin_amdgcn_mfma_f32_16x16x32_bf16(ahi, bhi, acc[d], 0, 0, 0);
            }
            __syncthreads();
            cur ^= 1;
        }
    }

    const int quad = lane >> 4;
    #pragma unroll
    for (int d = 0; d < 9; ++d) {
        #pragma unroll
        for (int g = 0; g < 4; ++g)
            scr[w][(quad * 4 + g) * 32 + nt * 16 + m15] = acc[d][g];
        __syncthreads();
        #pragma unroll
        for (int p = 0; p < 2; ++p) {
            const int idx = tid + 1024 * p;  // 1152 outputs per d
            if (p == 0 || tid < 128) {
                const int x  = idx / 9;
                const int dx = idx - x * 9;
                const int ww = x >> 4, m = x & 15;
                const float v = scr[ww][m * 32 + m + dx + 4] * (1.0f / 128.0f);
                cost[((size_t)r * W_ + x) * 81 + d * 9 + dx] = v;
            }
        }
        __syncthreads();                     // before next d overwrites scr
    }
}

// ---------------------------------------------------------------------------
// 3) weight prep: pw[CIN][COUT] fp32 -> bf16 hi/lo B-frag tiles
// ---------------------------------------------------------------------------
__global__ __launch_bounds__(256) void prep_kernel(
    const float* __restrict__ pw, int CIN, int COUT, int NT,
    unsigned short* __restrict__ hi, unsigned short* __restrict__ lo)
{
    const int kt = blockIdx.x / NT;
    const int nt = blockIdx.x - kt * NT;
    #pragma unroll
    for (int s = 0; s < 2; ++s) {
        const int e = threadIdx.x + 256 * s;
        const int n = e >> 5, k = e & 31;
        const int kg = kt * 32 + k, ng = nt * 16 + n;
        const float v = (kg < CIN && ng < COUT) ? pw[(size_t)kg * COUT + ng] : 0.0f;
        const unsigned short h = f2bf_rne(v);
        const unsigned short l = f2bf_rne(v - bf2f(h));
        const size_t o = ((size_t)blockIdx.x * 16 + n) * 32 + k;
        hi[o] = h; lo[o] = l;
    }
}

// ---------------------------------------------------------------------------
// 4) fused depthwise3x3(fp32) + pointwise MFMA (bf16 hi/lo), one block/row.
// R3: channel-vectorized depthwise (task = 4ch x 2px, float4 loads: 12/kt
// vs 36 scalar) + register prefetch of kt+1's loads across the MFMA phase
// (T14). Barrier moved to just before the A-write so depthwise VALU of kt
// overlaps the tail of kt-1's MFMA.
// ---------------------------------------------------------------------------
template<int CIN, int COUT, bool ACT, bool IS_L0>
__global__ __launch_bounds__(512, 4) void sepconv_kernel(
    const float* __restrict__ in,
    const float* __restrict__ cost, const float* __restrict__ prv,
    const float* __restrict__ flo,
    const float* __restrict__ dw,
    const unsigned short* __restrict__ Bhi, const unsigned short* __restrict__ Blo,
    const float* __restrict__ bias, float* __restrict__ out)
{
    constexpr int KT   = (CIN + 31) / 32;
    constexpr int KPAD = KT * 32;
    constexpr int NT   = (COUT + 15) / 16;
    constexpr int KSTR = 40;                 // ushort stride per px (80B, 16B-mult)
    __shared__ unsigned short Ahi[128 * KSTR];   // 10240 B
    __shared__ unsigned short Alo[128 * KSTR];   // 10240 B
    __shared__ float dwl[9 * KPAD];              // <= 8064 B

    const int tid  = threadIdx.x;
    const int lane = tid & 63;
    const int w    = tid >> 6;               // wave 0..7
    const int r    = swz_row(blockIdx.x);    // b*H + h
    const int h    = r & 127;
    const int b    = r >> 7;

    // depthwise task: co = 4-channel group within 32-chunk, xb = 2-px group
    const int co = (tid & 7) * 4;
    const int xb = (tid >> 3) * 2;

    // per-row validity (block-uniform) and base pixel index
    bool rowok[3]; int rowpix[3];
    #pragma unroll
    for (int ky = 0; ky < 3; ++ky) {
        const int yy = h + ky - 1;
        rowok[ky]  = (yy >= 0) && (yy < H_);
        rowpix[ky] = (b * H_ + (rowok[ky] ? yy : h)) * W_;
    }

    f32x4 V[3][4];                           // prefetched input window (48 VGPR)

    auto issue_loads = [&](int kt) {
        const int cg = kt * 32 + co;
        #pragma unroll
        for (int ky = 0; ky < 3; ++ky) {
            #pragma unroll
            for (int xm = 0; xm < 4; ++xm) {
                const int xx = xb - 1 + xm;
                f32x4 v = (f32x4){0.f, 0.f, 0.f, 0.f};
                if (rowok[ky] && xx >= 0 && xx < W_) {
                    const int px = rowpix[ky] + xx;
                    if constexpr (IS_L0) {
                        if (cg <= 76) {
                            v = load4u(cost + (size_t)px * 81 + cg);
                        } else if (cg == 80) {
                            const float* cp = cost + (size_t)px * 81;
                            const float* pp = prv + (size_t)px * 128;
                            v = (f32x4){cp[80], pp[0], pp[1], pp[2]};
                        } else if (cg <= 204) {
                            v = load4u(prv + (size_t)px * 128 + (cg - 81));
                        } else if (cg == 208) {
                            const float* pp = prv + (size_t)px * 128;
                            const float* fp = flo + (size_t)px * 2;
                            v = (f32x4){pp[127], fp[0], fp[1], 0.f};
                        }
                        // cg >= 212: stays zero (padded channels)
                    } else {
                        v = *(const f32x4*)(in + (size_t)px * CIN + cg);
                    }
                }
                V[ky][xm] = v;
            }
        }
    };

    issue_loads(0);                          // in flight under dwl staging

    // stage all depthwise weights once (zero-padded channels)
    for (int i = tid; i < 9 * KPAD; i += 512) {
        const int t = i / KPAD, c = i - t * KPAD;
        dwl[i] = (c < CIN) ? dw[t * CIN + c] : 0.0f;
    }

    f32x4 acc[NT];
    #pragma unroll
    for (int n = 0; n < NT; ++n)
        acc[n] = (f32x4){0.0f, 0.0f, 0.0f, 0.0f};

    __syncthreads();                         // dwl ready

    for (int kt = 0; kt < KT; ++kt) {
        // depthwise compute from prefetched V (VALU only; overlaps prev MFMA)
        const int cb = kt * 32 + co;
        f32x4 a0 = (f32x4){0.f, 0.f, 0.f, 0.f};
        f32x4 a1 = (f32x4){0.f, 0.f, 0.f, 0.f};
        #pragma unroll
        for (int ky = 0; ky < 3; ++ky) {
            #pragma unroll
            for (int kx = 0; kx < 3; ++kx) {
                const f32x4 wv = *(const f32x4*)&dwl[(ky * 3 + kx) * KPAD + cb];
                a0 += wv * V[ky][kx];
                a1 += wv * V[ky][kx + 1];
            }
        }

        if (kt + 1 < KT) issue_loads(kt + 1);    // fly across MFMA phase

        // hi/lo split into registers
        us4 h0, l0, h1, l1;
        #pragma unroll
        for (int j = 0; j < 4; ++j) {
            const unsigned short hh0 = f2bf_hw(a0[j]);
            h0[j] = hh0; l0[j] = f2bf_hw(a0[j] - bf2f(hh0));
            const unsigned short hh1 = f2bf_hw(a1[j]);
            h1[j] = hh1; l1[j] = f2bf_hw(a1[j] - bf2f(hh1));
        }

        __syncthreads();                     // prev MFMA done reading A
        *(us4*)&Ahi[(xb + 0) * KSTR + co] = h0;
        *(us4*)&Ahi[(xb + 1) * KSTR + co] = h1;
        *(us4*)&Alo[(xb + 0) * KSTR + co] = l0;
        *(us4*)&Alo[(xb + 1) * KSTR + co] = l1;
        __syncthreads();                     // A ready for this 32-chunk

        // MFMA sweep: wave w -> M-tile w
        const int mrow = w * 16 + (lane & 15);
        const int ko   = (lane >> 4) * 8;
        const s16x8 ahi = *(const s16x8*)&Ahi[mrow * KSTR + ko];
        const s16x8 alo = *(const s16x8*)&Alo[mrow * KSTR + ko];
        #pragma unroll
        for (int nt = 0; nt < NT; ++nt) {
            const size_t boff = (((size_t)(kt * NT + nt)) * 16 + (lane & 15)) * 32
                              + (size_t)ko;
            const s16x8 bhi = *(const s16x8*)&Bhi[boff];
            const s16x8 blo = *(const s16x8*)&Blo[boff];
            acc[nt] = __builtin_amdgcn_mfma_f32_16x16x32_bf16(alo, bhi, acc[nt], 0, 0, 0);
            acc[nt] = __builtin_amdgcn_mfma_f32_16x16x32_bf16(ahi, blo, acc[nt], 0, 0, 0);
            acc[nt] = __builtin_amdgcn_mfma_f32_16x16x32_bf16(ahi, bhi, acc[nt], 0, 0, 0);
        }
    }

    // epilogue: C/D layout col=lane&15 (n), row=quad*4+reg (px within tile)
    const int n    = lane & 15;
    const int quad = lane >> 4;
    #pragma unroll
    for (int nt = 0; nt < NT; ++nt) {
        const int o = nt * 16 + n;
        if ((COUT % 16 == 0) || (o < COUT)) {
            const float bv = ACT ? bias[o] : 0.0f;   // L5 has no bias
            #pragma unroll
            for (int reg = 0; reg < 4; ++reg) {
                const int px = w * 16 + quad * 4 + reg;
                const float v = acc[nt][reg] + bv;
                out[((size_t)r * W_ + px) * COUT + o] = ACT ? mish_f(v) : v;
            }
        }
    }
}

// ---------------------------------------------------------------------------
extern "C" void kernel_launch(void* const* d_in, const int* in_sizes, int n_in,
                              void* d_out, int out_size, void* d_ws, size_t ws_size,
                              hipStream_t stream)
{
    (void)in_sizes; (void)n_in; (void)out_size; (void)ws_size;
    const float* prv = (const float*)d_in[0];
    const float* nxt = (const float*)d_in[1];
    const float* flo = (const float*)d_in[2];
    const float* dw0 = (const float*)d_in[3];
    const float* pw0 = (const float*)d_in[4];
    const float* b0  = (const float*)d_in[5];
    const float* dw1 = (const float*)d_in[6];
    const float* pw1 = (const float*)d_in[7];
    const float* b1  = (const float*)d_in[8];
    const float* dw2 = (const float*)d_in[9];
    const float* pw2 = (const float*)d_in[10];
    const float* b2  = (const float*)d_in[11];
    const float* dw3 = (const float*)d_in[12];
    const float* pw3 = (const float*)d_in[13];
    const float* b3  = (const float*)d_in[14];
    const float* dw4 = (const float*)d_in[15];
    const float* pw4 = (const float*)d_in[16];
    const float* b4  = (const float*)d_in[17];
    const float* dw5 = (const float*)d_in[18];
    const float* pw5 = (const float*)d_in[19];

    char* ws = (char*)d_ws;
    float* bufA = (float*)ws;                               // [0, 64Mi)
    float* bufC = (float*)(ws + 67108864);                  // [64Mi, 128Mi)
    float* costb = bufC;                                    // 42.47 MB
    float* l4out = (float*)(ws + 67108864 + 33554432);      // bufC + 32Mi (16 MB)
    float* outp  = (float*)d_out;

    // weight regions (bf16 hi/lo tile arrays)
    unsigned short* W0h = (unsigned short*)(ws + 112000000);            // 57344 B
    unsigned short* W0l = (unsigned short*)(ws + 112000000 + 57344);
    unsigned short* W1h = (unsigned short*)d_out;                       // 32768 B
    unsigned short* W1l = (unsigned short*)d_out + 16384;
    unsigned short* W2h = (unsigned short*)(ws + 50331648);             // 24576 B
    unsigned short* W2l = (unsigned short*)(ws + 50356224);
    unsigned short* W3h = (unsigned short*)(ws + 50380800);             // 12288 B
    unsigned short* W3l = (unsigned short*)(ws + 50393088);
    unsigned short* W4h = (unsigned short*)(ws + 50405376);             //  4096 B
    unsigned short* W4l = (unsigned short*)(ws + 50409472);
    unsigned short* W5h = (unsigned short*)(ws + 50413568);             //  1024 B
    unsigned short* W5l = (unsigned short*)(ws + 50414592);

    const float* nullf = nullptr;

    warp_kernel<<<65536, 256, 0, stream>>>(nxt, flo, bufA);
    costvol_mfma_kernel<<<1024, 1024, 0, stream>>>(prv, bufA, costb);

    prep_kernel<<<7 * 8, 256, 0, stream>>>(pw0, 211, 128, 8, W0h, W0l);
    prep_kernel<<<4 * 8, 256, 0, stream>>>(pw1, 128, 128, 8, W1h, W1l);

    // L0: 211 -> 128, reads [cost|prv|flo], writes bufA (nxtw dead)
    sepconv_kernel<211, 128, true,  true ><<<1024, 512, 0, stream>>>(
        nullf, costb, prv, flo, dw0, W0h, W0l, b0, bufA);
    // L1: 128 -> 128, bufA -> bufC (cost + W0 dead)
    sepconv_kernel<128, 128, true,  false><<<1024, 512, 0, stream>>>(
        bufA, nullf, nullf, nullf, dw1, W1h, W1l, b1, bufC);

    // bufA now dead -> prep remaining weights into its tail
    prep_kernel<<<4 * 6, 256, 0, stream>>>(pw2, 128,  96, 6, W2h, W2l);
    prep_kernel<<<3 * 4, 256, 0, stream>>>(pw3,  96,  64, 4, W3h, W3l);
    prep_kernel<<<2 * 2, 256, 0, stream>>>(pw4,  64,  32, 2, W4h, W4l);
    prep_kernel<<<1 * 1, 256, 0, stream>>>(pw5,  32,   2, 1, W5h, W5l);

    // L2: 128 -> 96, bufC -> bufA[0,48Mi)
    sepconv_kernel<128,  96, true,  false><<<1024, 512, 0, stream>>>(
        bufC, nullf, nullf, nullf, dw2, W2h, W2l, b2, bufA);
    // L3: 96 -> 64, bufA -> bufC[0,32Mi) (L1 out dead)
    sepconv_kernel< 96,  64, true,  false><<<1024, 512, 0, stream>>>(
        bufA, nullf, nullf, nullf, dw3, W3h, W3l, b3, bufC);
    // L4: 64 -> 32, bufC[0,32Mi) -> bufC[32Mi,48Mi)
    sepconv_kernel< 64,  32, true,  false><<<1024, 512, 0, stream>>>(
        bufC, nullf, nullf, nullf, dw4, W4h, W4l, b4, l4out);
    // L5: 32 -> 2, -> d_out (overwrites W1)
    sepconv_kernel< 32,   2, false, false><<<1024, 512, 0, stream>>>(
        l4out, nullf, nullf, nullf, dw5, W5h, W5l, nullf, outp);
}

// Round 4
// 590.066 us; speedup vs baseline: 2.0015x; 2.0015x over previous
//
#include <hip/hip_runtime.h>
#include <hip/hip_bf16.h>

#define B_ 8
#define H_ 128
#define W_ 128
#define C_ 128

using f32x4 = __attribute__((ext_vector_type(4))) float;
using s16x8 = __attribute__((ext_vector_type(8))) short;
using us4   = __attribute__((ext_vector_type(4))) unsigned short;

// mish(x) = x * tanh(softplus(x)) = x * (t^2 + 2t) / (t^2 + 2t + 2), t = e^x
__device__ __forceinline__ float mish_f(float x) {
    float t = __expf(fminf(x, 20.0f));
    float u = t * (t + 2.0f);
    return x * u / (u + 2.0f);
}

__device__ __forceinline__ int swz_row(int blk) {
    return ((blk & 7) << 7) | (blk >> 3);
}

// fp32 -> bf16 round-to-nearest-even on raw bits
__device__ __forceinline__ unsigned short f2bf_rne(float x) {
    unsigned u = __builtin_bit_cast(unsigned, x);
    u += 0x7FFFu + ((u >> 16) & 1u);
    return (unsigned short)(u >> 16);
}
__device__ __forceinline__ float bf2f(unsigned short h) {
    unsigned u = ((unsigned)h) << 16;
    return __builtin_bit_cast(float, u);
}
// hw conversion path (RNE, same bits as f2bf_rne for finite inputs)
__device__ __forceinline__ unsigned short f2bf_hw(float x) {
    return __bfloat16_as_ushort(__float2bfloat16(x));
}

// unaligned (4B-aligned) float4 load
__device__ __forceinline__ f32x4 load4u(const float* p) {
    f32x4 v;
    __builtin_memcpy(&v, p, 16);
    return v;
}

// ---------------------------------------------------------------------------
// 1) bilinear backward warp
// ---------------------------------------------------------------------------
__global__ __launch_bounds__(256) void warp_kernel(
    const float* __restrict__ nxt, const float* __restrict__ flo,
    float* __restrict__ nxtw)
{
    const int tid = threadIdx.x;
    const int c   = tid & 127;
    const int pix = blockIdx.x * 2 + (tid >> 7);
    const int b   = pix >> 14;
    const int rem = pix & 16383;
    const int y   = rem >> 7;
    const int x   = rem & 127;

    const float fx = flo[(size_t)pix * 2 + 0];
    const float fy = flo[(size_t)pix * 2 + 1];
    const float xf = (float)x + fx;
    const float yf = (float)y + fy;
    const int x0 = (int)xf;
    const int y0 = (int)yf;
    const int x0c = min(max(x0, 0), W_ - 1);
    const int x1c = min(max(x0 + 1, 0), W_ - 1);
    const int y0c = min(max(y0, 0), H_ - 1);
    const int y1c = min(max(y0 + 1, 0), H_ - 1);
    const float x0f = (float)x0c, x1f = (float)x1c;
    const float y0f = (float)y0c, y1f = (float)y1c;
    const float wa = (x1f - xf) * (y1f - yf);
    const float wb = (x1f - xf) * (yf - y0f);
    const float wc = (xf - x0f) * (y1f - yf);
    const float wd = (xf - x0f) * (yf - y0f);

    const float* base = nxt + (size_t)b * H_ * W_ * C_;
    const float Ia = base[((size_t)y0c * W_ + x0c) * C_ + c];
    const float Ib = base[((size_t)y1c * W_ + x0c) * C_ + c];
    const float Ic = base[((size_t)y0c * W_ + x1c) * C_ + c];
    const float Id = base[((size_t)y1c * W_ + x1c) * C_ + c];
    nxtw[(size_t)pix * C_ + c] = wa * Ia + wb * Ib + wc * Ic + wd * Id;
}

// ---------------------------------------------------------------------------
// 2) cost volume via MFMA (verified in R2: off the critical path)
// ---------------------------------------------------------------------------
__global__ __launch_bounds__(1024, 4) void costvol_mfma_kernel(
    const float* __restrict__ prv, const float* __restrict__ nxtw,
    float* __restrict__ cost)
{
    constexpr int NSTR = 40;                 // shorts per s-position (80 B, 16B-mult)
    __shared__ unsigned short Nhi[2][144 * NSTR];   // 11520 B each buf
    __shared__ unsigned short Nlo[2][144 * NSTR];
    __shared__ float scr[8][512];                   // 16 KB epilogue scratch

    const int tid  = threadIdx.x;
    const int lane = tid & 63;
    const int wv   = tid >> 6;               // 0..15
    const int w    = wv >> 1;                // x-tile 0..7
    const int nt   = wv & 1;                 // n-half 0..1
    const int r    = swz_row(blockIdx.x);    // b*H + y
    const int y    = r & 127;
    const int b    = r >> 7;
    const int ko   = (lane >> 4) * 8;        // k offset within 32-chunk
    const int m15  = lane & 15;

    auto stageN = [&](int q, int kt, int bb) {
        if (q < 0 || q >= H_) return;        // invalid row: never read (MFMA skipped)
        const float* nb = nxtw + ((size_t)(b * H_ + q) * W_) * C_ + kt * 32;
        #pragma unroll
        for (int p = 0; p < 2; ++p) {
            const int idx = tid + 1024 * p;  // 1152 float4 tasks
            if (p == 0 || tid < 128) {
                const int sm = idx >> 3;
                const int c4 = (idx & 7) * 4;
                const int gx = sm - 8;
                float4 v = make_float4(0.f, 0.f, 0.f, 0.f);
                if (gx >= 0 && gx < W_)
                    v = *(const float4*)&nb[(size_t)gx * C_ + c4];
                us4 hv, lv;
                #pragma unroll
                for (int j = 0; j < 4; ++j) {
                    const float f = ((const float*)&v)[j];
                    const unsigned short hh = f2bf_hw(f);
                    hv[j] = hh;
                    lv[j] = f2bf_hw(f - bf2f(hh));
                }
                *(us4*)&Nhi[bb][sm * NSTR + c4] = hv;
                *(us4*)&Nlo[bb][sm * NSTR + c4] = lv;
            }
        }
    };

    f32x4 acc[9];
    #pragma unroll
    for (int d = 0; d < 9; ++d) acc[d] = (f32x4){0.f, 0.f, 0.f, 0.f};

    const float* pbase = prv + ((size_t)r * W_ + (w * 16 + m15)) * C_;
    float4 pf0 = *(const float4*)&pbase[ko];
    float4 pf1 = *(const float4*)&pbase[ko + 4];

    stageN(y - 4, 0, 0);                     // prologue: step (0,0)
    __syncthreads();

    int cur = 0;
    s16x8 ahi, alo;
    for (int kt = 0; kt < 4; ++kt) {
        #pragma unroll
        for (int d = 0; d < 9; ++d) {
            if (d == 0) {                    // convert prefetched P chunk -> A frags
                #pragma unroll
                for (int j = 0; j < 8; ++j) {
                    const float f = (j < 4) ? ((const float*)&pf0)[j]
                                            : ((const float*)&pf1)[j - 4];
                    const unsigned short hh = f2bf_hw(f);
                    ahi[j] = (short)hh;
                    alo[j] = (short)f2bf_hw(f - bf2f(hh));
                }
            }
            if (d == 5 && kt < 3) {          // prefetch next P chunk
                pf0 = *(const float4*)&pbase[(kt + 1) * 32 + ko];
                pf1 = *(const float4*)&pbase[(kt + 1) * 32 + ko + 4];
            }
            {
                const int nkt = (d == 8) ? kt + 1 : kt;
                const int nd  = (d == 8) ? 0 : d + 1;
                if (nkt < 4) stageN(y + nd - 4, nkt, cur ^ 1);
            }
            const int q = y + d - 4;
            if (q >= 0 && q < H_) {
                const int boff = (w * 16 + nt * 16 + m15) * NSTR + ko;
                const s16x8 bhi = *(const s16x8*)&Nhi[cur][boff];
                const s16x8 blo = *(const s16x8*)&Nlo[cur][boff];
                acc[d] = __builtin_amdgcn_mfma_f32_16x16x32_bf16(alo, bhi, acc[d], 0, 0, 0);
                acc[d] = __builtin_amdgcn_mfma_f32_16x16x32_bf16(ahi, blo, acc[d], 0, 0, 0);
                acc[d] = __builtin_amdgcn_mfma_f32_16x16x32_bf16(ahi, bhi, acc[d], 0, 0, 0);
            }
            __syncthreads();
            cur ^= 1;
        }
    }

    const int quad = lane >> 4;
    #pragma unroll
    for (int d = 0; d < 9; ++d) {
        #pragma unroll
        for (int g = 0; g < 4; ++g)
            scr[w][(quad * 4 + g) * 32 + nt * 16 + m15] = acc[d][g];
        __syncthreads();
        #pragma unroll
        for (int p = 0; p < 2; ++p) {
            const int idx = tid + 1024 * p;  // 1152 outputs per d
            if (p == 0 || tid < 128) {
                const int x  = idx / 9;
                const int dx = idx - x * 9;
                const int ww = x >> 4, m = x & 15;
                const float v = scr[ww][m * 32 + m + dx + 4] * (1.0f / 128.0f);
                cost[((size_t)r * W_ + x) * 81 + d * 9 + dx] = v;
            }
        }
        __syncthreads();                     // before next d overwrites scr
    }
}

// ---------------------------------------------------------------------------
// 3) weight prep: pw[CIN][COUT] fp32 -> bf16 hi/lo B-frag tiles
// ---------------------------------------------------------------------------
__global__ __launch_bounds__(256) void prep_kernel(
    const float* __restrict__ pw, int CIN, int COUT, int NT,
    unsigned short* __restrict__ hi, unsigned short* __restrict__ lo)
{
    const int kt = blockIdx.x / NT;
    const int nt = blockIdx.x - kt * NT;
    #pragma unroll
    for (int s = 0; s < 2; ++s) {
        const int e = threadIdx.x + 256 * s;
        const int n = e >> 5, k = e & 31;
        const int kg = kt * 32 + k, ng = nt * 16 + n;
        const float v = (kg < CIN && ng < COUT) ? pw[(size_t)kg * COUT + ng] : 0.0f;
        const unsigned short h = f2bf_rne(v);
        const unsigned short l = f2bf_rne(v - bf2f(h));
        const size_t o = ((size_t)blockIdx.x * 16 + n) * 32 + k;
        hi[o] = h; lo[o] = l;
    }
}

// ---------------------------------------------------------------------------
// 4) fused depthwise3x3(fp32) + pointwise MFMA (bf16 hi/lo), one block/row.
// R4: channel-vectorized depthwise task (4ch x 2px, 12 float4 loads per kt
// vs 36 scalar in R2) with IMMEDIATE consumption — V's live range stays
// inside one iteration and crosses no barrier (R3's cross-MFMA register
// prefetch spilled to scratch: 10x HBM traffic). Overlap comes free from
// loop order: iteration kt+1's loads issue right after kt's MFMAs with no
// intervening barrier.
// ---------------------------------------------------------------------------
template<int CIN, int COUT, bool ACT, bool IS_L0>
__global__ __launch_bounds__(512, 4) void sepconv_kernel(
    const float* __restrict__ in,
    const float* __restrict__ cost, const float* __restrict__ prv,
    const float* __restrict__ flo,
    const float* __restrict__ dw,
    const unsigned short* __restrict__ Bhi, const unsigned short* __restrict__ Blo,
    const float* __restrict__ bias, float* __restrict__ out)
{
    constexpr int KT   = (CIN + 31) / 32;
    constexpr int KPAD = KT * 32;
    constexpr int NT   = (COUT + 15) / 16;
    constexpr int KSTR = 40;                 // ushort stride per px (80B, 16B-mult)
    __shared__ unsigned short Ahi[128 * KSTR];   // 10240 B
    __shared__ unsigned short Alo[128 * KSTR];   // 10240 B
    __shared__ float dwl[9 * KPAD];              // <= 8064 B

    const int tid  = threadIdx.x;
    const int lane = tid & 63;
    const int w    = tid >> 6;               // wave 0..7
    const int r    = swz_row(blockIdx.x);    // b*H + h
    const int h    = r & 127;
    const int b    = r >> 7;

    // depthwise task: co = 4-channel group within 32-chunk, xb = 2-px group
    const int co = (tid & 7) * 4;
    const int xb = (tid >> 3) * 2;

    // per-row validity (block-uniform) and base pixel index
    bool rowok[3]; int rowpix[3];
    #pragma unroll
    for (int ky = 0; ky < 3; ++ky) {
        const int yy = h + ky - 1;
        rowok[ky]  = (yy >= 0) && (yy < H_);
        rowpix[ky] = (b * H_ + (rowok[ky] ? yy : h)) * W_;
    }

    // stage all depthwise weights once (zero-padded channels)
    for (int i = tid; i < 9 * KPAD; i += 512) {
        const int t = i / KPAD, c = i - t * KPAD;
        dwl[i] = (c < CIN) ? dw[t * CIN + c] : 0.0f;
    }

    f32x4 acc[NT];
    #pragma unroll
    for (int n = 0; n < NT; ++n)
        acc[n] = (f32x4){0.0f, 0.0f, 0.0f, 0.0f};

    __syncthreads();                         // dwl ready

    for (int kt = 0; kt < KT; ++kt) {
        // ---- load input window for this kt (12 float4, issued back-to-back;
        //      overlaps the previous iteration's MFMA drain) ----
        const int cg = kt * 32 + co;
        f32x4 V[3][4];
        #pragma unroll
        for (int ky = 0; ky < 3; ++ky) {
            #pragma unroll
            for (int xm = 0; xm < 4; ++xm) {
                const int xx = xb - 1 + xm;
                f32x4 v = (f32x4){0.f, 0.f, 0.f, 0.f};
                if (rowok[ky] && xx >= 0 && xx < W_) {
                    const int px = rowpix[ky] + xx;
                    if constexpr (IS_L0) {
                        if (cg <= 76) {
                            v = load4u(cost + (size_t)px * 81 + cg);
                        } else if (cg == 80) {
                            const float* cp = cost + (size_t)px * 81;
                            const float* pp = prv + (size_t)px * 128;
                            v = (f32x4){cp[80], pp[0], pp[1], pp[2]};
                        } else if (cg <= 204) {
                            v = load4u(prv + (size_t)px * 128 + (cg - 81));
                        } else if (cg == 208) {
                            const float* pp = prv + (size_t)px * 128;
                            const float* fp = flo + (size_t)px * 2;
                            v = (f32x4){pp[127], fp[0], fp[1], 0.f};
                        }
                        // cg >= 212: stays zero (padded channels)
                    } else {
                        v = *(const f32x4*)(in + (size_t)px * CIN + cg);
                    }
                }
                V[ky][xm] = v;
            }
        }

        // ---- depthwise compute (VALU only) ----
        f32x4 a0 = (f32x4){0.f, 0.f, 0.f, 0.f};
        f32x4 a1 = (f32x4){0.f, 0.f, 0.f, 0.f};
        #pragma unroll
        for (int ky = 0; ky < 3; ++ky) {
            #pragma unroll
            for (int kx = 0; kx < 3; ++kx) {
                const f32x4 wv = *(const f32x4*)&dwl[(ky * 3 + kx) * KPAD + cg - kt * 32 + kt * 32];
                a0 += wv * V[ky][kx];
                a1 += wv * V[ky][kx + 1];
            }
        }

        // hi/lo split into registers
        us4 h0, l0, h1, l1;
        #pragma unroll
        for (int j = 0; j < 4; ++j) {
            const unsigned short hh0 = f2bf_hw(a0[j]);
            h0[j] = hh0; l0[j] = f2bf_hw(a0[j] - bf2f(hh0));
            const unsigned short hh1 = f2bf_hw(a1[j]);
            h1[j] = hh1; l1[j] = f2bf_hw(a1[j] - bf2f(hh1));
        }

        __syncthreads();                     // prev MFMA done reading A
        *(us4*)&Ahi[(xb + 0) * KSTR + co] = h0;
        *(us4*)&Ahi[(xb + 1) * KSTR + co] = h1;
        *(us4*)&Alo[(xb + 0) * KSTR + co] = l0;
        *(us4*)&Alo[(xb + 1) * KSTR + co] = l1;
        __syncthreads();                     // A ready for this 32-chunk

        // MFMA sweep: wave w -> M-tile w
        const int mrow = w * 16 + (lane & 15);
        const int ko   = (lane >> 4) * 8;
        const s16x8 ahi = *(const s16x8*)&Ahi[mrow * KSTR + ko];
        const s16x8 alo = *(const s16x8*)&Alo[mrow * KSTR + ko];
        #pragma unroll
        for (int nt = 0; nt < NT; ++nt) {
            const size_t boff = (((size_t)(kt * NT + nt)) * 16 + (lane & 15)) * 32
                              + (size_t)ko;
            const s16x8 bhi = *(const s16x8*)&Bhi[boff];
            const s16x8 blo = *(const s16x8*)&Blo[boff];
            acc[nt] = __builtin_amdgcn_mfma_f32_16x16x32_bf16(alo, bhi, acc[nt], 0, 0, 0);
            acc[nt] = __builtin_amdgcn_mfma_f32_16x16x32_bf16(ahi, blo, acc[nt], 0, 0, 0);
            acc[nt] = __builtin_amdgcn_mfma_f32_16x16x32_bf16(ahi, bhi, acc[nt], 0, 0, 0);
        }
    }

    // epilogue: C/D layout col=lane&15 (n), row=quad*4+reg (px within tile)
    const int n    = lane & 15;
    const int quad = lane >> 4;
    #pragma unroll
    for (int nt = 0; nt < NT; ++nt) {
        const int o = nt * 16 + n;
        if ((COUT % 16 == 0) || (o < COUT)) {
            const float bv = ACT ? bias[o] : 0.0f;   // L5 has no bias
            #pragma unroll
            for (int reg = 0; reg < 4; ++reg) {
                const int px = w * 16 + quad * 4 + reg;
                const float v = acc[nt][reg] + bv;
                out[((size_t)r * W_ + px) * COUT + o] = ACT ? mish_f(v) : v;
            }
        }
    }
}

// ---------------------------------------------------------------------------
extern "C" void kernel_launch(void* const* d_in, const int* in_sizes, int n_in,
                              void* d_out, int out_size, void* d_ws, size_t ws_size,
                              hipStream_t stream)
{
    (void)in_sizes; (void)n_in; (void)out_size; (void)ws_size;
    const float* prv = (const float*)d_in[0];
    const float* nxt = (const float*)d_in[1];
    const float* flo = (const float*)d_in[2];
    const float* dw0 = (const float*)d_in[3];
    const float* pw0 = (const float*)d_in[4];
    const float* b0  = (const float*)d_in[5];
    const float* dw1 = (const float*)d_in[6];
    const float* pw1 = (const float*)d_in[7];
    const float* b1  = (const float*)d_in[8];
    const float* dw2 = (const float*)d_in[9];
    const float* pw2 = (const float*)d_in[10];
    const float* b2  = (const float*)d_in[11];
    const float* dw3 = (const float*)d_in[12];
    const float* pw3 = (const float*)d_in[13];
    const float* b3  = (const float*)d_in[14];
    const float* dw4 = (const float*)d_in[15];
    const float* pw4 = (const float*)d_in[16];
    const float* b4  = (const float*)d_in[17];
    const float* dw5 = (const float*)d_in[18];
    const float* pw5 = (const float*)d_in[19];

    char* ws = (char*)d_ws;
    float* bufA = (float*)ws;                               // [0, 64Mi)
    float* bufC = (float*)(ws + 67108864);                  // [64Mi, 128Mi)
    float* costb = bufC;                                    // 42.47 MB
    float* l4out = (float*)(ws + 67108864 + 33554432);      // bufC + 32Mi (16 MB)
    float* outp  = (float*)d_out;

    // weight regions (bf16 hi/lo tile arrays)
    unsigned short* W0h = (unsigned short*)(ws + 112000000);            // 57344 B
    unsigned short* W0l = (unsigned short*)(ws + 112000000 + 57344);
    unsigned short* W1h = (unsigned short*)d_out;                       // 32768 B
    unsigned short* W1l = (unsigned short*)d_out + 16384;
    unsigned short* W2h = (unsigned short*)(ws + 50331648);             // 24576 B
    unsigned short* W2l = (unsigned short*)(ws + 50356224);
    unsigned short* W3h = (unsigned short*)(ws + 50380800);             // 12288 B
    unsigned short* W3l = (unsigned short*)(ws + 50393088);
    unsigned short* W4h = (unsigned short*)(ws + 50405376);             //  4096 B
    unsigned short* W4l = (unsigned short*)(ws + 50409472);
    unsigned short* W5h = (unsigned short*)(ws + 50413568);             //  1024 B
    unsigned short* W5l = (unsigned short*)(ws + 50414592);

    const float* nullf = nullptr;

    warp_kernel<<<65536, 256, 0, stream>>>(nxt, flo, bufA);
    costvol_mfma_kernel<<<1024, 1024, 0, stream>>>(prv, bufA, costb);

    prep_kernel<<<7 * 8, 256, 0, stream>>>(pw0, 211, 128, 8, W0h, W0l);
    prep_kernel<<<4 * 8, 256, 0, stream>>>(pw1, 128, 128, 8, W1h, W1l);

    // L0: 211 -> 128, reads [cost|prv|flo], writes bufA (nxtw dead)
    sepconv_kernel<211, 128, true,  true ><<<1024, 512, 0, stream>>>(
        nullf, costb, prv, flo, dw0, W0h, W0l, b0, bufA);
    // L1: 128 -> 128, bufA -> bufC (cost + W0 dead)
    sepconv_kernel<128, 128, true,  false><<<1024, 512, 0, stream>>>(
        bufA, nullf, nullf, nullf, dw1, W1h, W1l, b1, bufC);

    // bufA now dead -> prep remaining weights into its tail
    prep_kernel<<<4 * 6, 256, 0, stream>>>(pw2, 128,  96, 6, W2h, W2l);
    prep_kernel<<<3 * 4, 256, 0, stream>>>(pw3,  96,  64, 4, W3h, W3l);
    prep_kernel<<<2 * 2, 256, 0, stream>>>(pw4,  64,  32, 2, W4h, W4l);
    prep_kernel<<<1 * 1, 256, 0, stream>>>(pw5,  32,   2, 1, W5h, W5l);

    // L2: 128 -> 96, bufC -> bufA[0,48Mi)
    sepconv_kernel<128,  96, true,  false><<<1024, 512, 0, stream>>>(
        bufC, nullf, nullf, nullf, dw2, W2h, W2l, b2, bufA);
    // L3: 96 -> 64, bufA -> bufC[0,32Mi) (L1 out dead)
    sepconv_kernel< 96,  64, true,  false><<<1024, 512, 0, stream>>>(
        bufA, nullf, nullf, nullf, dw3, W3h, W3l, b3, bufC);
    // L4: 64 -> 32, bufC[0,32Mi) -> bufC[32Mi,48Mi)
    sepconv_kernel< 64,  32, true,  false><<<1024, 512, 0, stream>>>(
        bufC, nullf, nullf, nullf, dw4, W4h, W4l, b4, l4out);
    // L5: 32 -> 2, -> d_out (overwrites W1)
    sepconv_kernel< 32,   2, false, false><<<1024, 512, 0, stream>>>(
        l4out, nullf, nullf, nullf, dw5, W5h, W5l, nullf, outp);
}